// Round 9
// baseline (222.574 us; speedup 1.0000x reference)
//
#include <hip/hip_runtime.h>
#include <stdint.h>

typedef __attribute__((ext_vector_type(8))) short short8;
typedef __attribute__((ext_vector_type(4))) short short4v;
typedef __attribute__((ext_vector_type(4))) float f32x4;
typedef __attribute__((ext_vector_type(16))) float f32x16;
typedef __attribute__((ext_vector_type(2))) unsigned int u32x2;
typedef unsigned int u32;
typedef const __attribute__((address_space(1))) u32* gas_ptr;
typedef __attribute__((address_space(3))) u32* las_ptr;

#define QSCALE 0.18033688011112042f   // 0.125 * log2(e)

__device__ inline short f2bf(float x) {
    u32 u = __float_as_uint(x);
    u = u + 0x7FFFu + ((u >> 16) & 1u);   // RNE
    return (short)(u >> 16);
}
__device__ inline float bf2f(short b) {
    return __uint_as_float(((u32)(unsigned short)b) << 16);
}
__device__ inline void gload16(const void* g, const void* l) {
    __builtin_amdgcn_global_load_lds((gas_ptr)g, (las_ptr)l, 16, 0, 0);
}

// ---------------------------------------------------------------------------
// prep: all fp32->bf16 converts + strata fold (transposed) + bc matvec.
// ---------------------------------------------------------------------------
__global__ __launch_bounds__(256) void prep(const float* __restrict__ X,
                                            const float* __restrict__ Wq,
                                            const float* __restrict__ Wk,
                                            const float* __restrict__ Wv,
                                            const float* __restrict__ Wo,
                                            const float* __restrict__ Ws,
                                            const float* __restrict__ bs,
                                            const float* __restrict__ bo,
                                            short* __restrict__ Xb,
                                            short* __restrict__ Wcat,
                                            short* __restrict__ Wob,
                                            short* __restrict__ WmT,
                                            float* __restrict__ bc) {
    __shared__ short T[64][65];
    const int tid = threadIdx.x;
    const int bid = blockIdx.x;
    if (bid < 8192) {
        const float* src;
        short* dst;
        int rel;
        if (bid < 4096)      { src = X;  dst = Xb;                rel = bid; }
        else if (bid < 5120) { src = Wq; dst = Wcat;              rel = bid - 4096; }
        else if (bid < 6144) { src = Wk; dst = Wcat + (1 << 20);  rel = bid - 5120; }
        else if (bid < 7168) { src = Wv; dst = Wcat + (2 << 20);  rel = bid - 6144; }
        else                 { src = Wo; dst = Wob;               rel = bid - 7168; }
        int i = (rel * 256 + tid) * 4;
        float4 v = *(const float4*)&src[i];
        short4v o;
        o[0] = f2bf(v.x); o[1] = f2bf(v.y); o[2] = f2bf(v.z); o[3] = f2bf(v.w);
        *(short4v*)&dst[i] = o;
    } else if (bid < 8448) {
        const int id = bid - 8192;
        const int gx = (id & 15) * 64, jy = (id >> 4) * 64;
        const int HH = 1 << 20;
        for (int e = tid; e < 4096; e += 256) {
            int j = e >> 6, g = e & 63;
            int idx = (jy + j) * 1024 + gx + g;
            float v = (Ws[idx] + Ws[idx + HH] + Ws[idx + 2 * HH]) * (1.0f / 3.0f);
            T[g][j] = f2bf(v);
        }
        __syncthreads();
        for (int e = tid; e < 4096; e += 256) {
            int g = e >> 6, j = e & 63;
            WmT[(long)(gx + g) * 1024 + jy + j] = T[g][j];
        }
    } else {
        const int lane = tid & 63;
        const int n = (bid - 8448) * 4 + (tid >> 6);
        float acc = 0.0f;
        for (int j0 = 0; j0 < 1024; j0 += 64) {
            int j = j0 + lane;
            float bm = (bs[j] + bs[j + 1024] + bs[j + 2048]) * (1.0f / 3.0f);
            acc += Wo[(long)n * 1024 + j] * bm;
        }
#pragma unroll
        for (int off = 1; off < 64; off <<= 1) acc += __shfl_xor(acc, off, 64);
        if (lane == 0) bc[n] = acc + bo[n];
    }
}

// ---------------------------------------------------------------------------
// Fused QKV + Wc GEMM, 64x128 tiles, BK=64, XOR-8 swizzled LDS. 1664 blocks.
// Q pre-scaled by QSCALE; V stored transposed per-head.
// ---------------------------------------------------------------------------
__global__ __launch_bounds__(256) void gemm_qkvwc(const short* __restrict__ Xb,
                                                  const short* __restrict__ Wcat,
                                                  const short* __restrict__ Wob,
                                                  const short* __restrict__ WmT,
                                                  const float* __restrict__ bq,
                                                  const float* __restrict__ bk,
                                                  const float* __restrict__ bv,
                                                  short* __restrict__ Qb,
                                                  short* __restrict__ Kb,
                                                  short* __restrict__ Vt,
                                                  short* __restrict__ Wc) {
    __shared__ short As[64 * 64];
    __shared__ short Bs[128 * 64];
    const int K = 1024;
    const int tid  = threadIdx.x;
    const int lane = tid & 63;
    const int wave = tid >> 6;
    const int quad = lane >> 4;
    const int l16  = lane & 15;
    const int bid = blockIdx.x;
    const short *A, *W;
    int m0, n0, sel;
    if (bid < 1536) {
        sel = bid >> 9;
        int r = bid & 511;
        m0 = (r >> 3) * 64;
        n0 = (r & 7) * 128;
        A = Xb;
        W = Wcat + (long)sel * (1 << 20);
    } else {
        int w = bid - 1536;
        sel = 3;
        m0 = (w >> 3) * 64;
        n0 = (w & 7) * 128;
        A = Wob;
        W = WmT;
    }
    const int wm = (wave >> 1) * 32;
    const int wn = (wave & 1) * 64;

    f32x4 acc[2][4] = {};
    const int sr = tid >> 3;
    const int scol = (((tid & 7) ^ (sr & 7)) << 3);
    const int fo_a = ((quad ^ (l16 & 7)) << 3);
    const int fo_b = (((4 + quad) ^ (l16 & 7)) << 3);

    for (int k0 = 0; k0 < K; k0 += 64) {
#pragma unroll
        for (int i = 0; i < 2; i++) {
            int r = i * 32 + sr;
            gload16(&A[(long)(m0 + r) * K + k0 + scol], &As[i * 2048 + wave * 512]);
        }
#pragma unroll
        for (int i = 0; i < 4; i++) {
            int r = i * 32 + sr;
            gload16(&W[(long)(n0 + r) * K + k0 + scol], &Bs[i * 2048 + wave * 512]);
        }
        __syncthreads();
        short8 bfr[4][2];
#pragma unroll
        for (int ni = 0; ni < 4; ni++) {
            const int row = wn + ni * 16 + l16;
            bfr[ni][0] = *(short8*)&Bs[row * 64 + fo_a];
            bfr[ni][1] = *(short8*)&Bs[row * 64 + fo_b];
        }
#pragma unroll
        for (int mi = 0; mi < 2; mi++) {
            const int row = wm + mi * 16 + l16;
            short8 af0 = *(short8*)&As[row * 64 + fo_a];
            short8 af1 = *(short8*)&As[row * 64 + fo_b];
#pragma unroll
            for (int ni = 0; ni < 4; ni++) {
                acc[mi][ni] = __builtin_amdgcn_mfma_f32_16x16x32_bf16(af0, bfr[ni][0],
                                                                      acc[mi][ni], 0, 0, 0);
                acc[mi][ni] = __builtin_amdgcn_mfma_f32_16x16x32_bf16(af1, bfr[ni][1],
                                                                      acc[mi][ni], 0, 0, 0);
            }
        }
        __syncthreads();
    }

#pragma unroll
    for (int mi = 0; mi < 2; mi++) {
#pragma unroll
        for (int ni = 0; ni < 4; ni++) {
            const int n = n0 + wn + ni * 16 + l16;
            const int mbase = m0 + wm + mi * 16 + quad * 4;
            float bv2 = 0.0f;
            if (sel == 0) bv2 = bq[n];
            else if (sel == 1) bv2 = bk[n];
            else if (sel == 2) bv2 = bv[n];
            if (sel == 2) {
                short4v pk;
#pragma unroll
                for (int r = 0; r < 4; r++) pk[r] = f2bf(acc[mi][ni][r] + bv2);
                long addr = ((long)(mbase >> 11) << 21) + (long)n * 2048 + (mbase & 2047);
                *(short4v*)&Vt[addr] = pk;
            } else if (sel == 0) {
#pragma unroll
                for (int r = 0; r < 4; r++)
                    Qb[(long)(mbase + r) * 1024 + n] = f2bf((acc[mi][ni][r] + bv2) * QSCALE);
            } else {
                short* C = (sel == 1) ? Kb : Wc;
#pragma unroll
                for (int r = 0; r < 4; r++)
                    C[(long)(mbase + r) * 1024 + n] = f2bf(acc[mi][ni][r] + bv2);
            }
        }
    }
}

// ---------------------------------------------------------------------------
// Flash attention v4: 32x32x16 MFMA, kv-split 2 (linear unnormalized softmax).
// grid (32 = 16 qt x 2 split, 16 h, 2 b). Each block: 128 q x 1024 kv.
// Writes normalized partial O (bf16) to Pp[split] and row-sum l to L[split].
// ---------------------------------------------------------------------------
__global__ __launch_bounds__(256) void attn_kernel(const short* __restrict__ Q,
                                                   const short* __restrict__ Kb,
                                                   const short* __restrict__ Vt,
                                                   short* __restrict__ Pp,
                                                   float* __restrict__ L) {
    __shared__ short Ks[2][64 * 64];
    __shared__ short Vs[64 * 64];
    __shared__ short Ps[4][32 * 64];
    const int tid  = threadIdx.x;
    const int lane = tid & 63;
    const int wave = tid >> 6;
    const int l32  = lane & 31;
    const int hi   = lane >> 5;
    const int sw   = l32 & 7;
    const int qt    = blockIdx.x & 15;
    const int split = blockIdx.x >> 4;
    const int q0 = qt * 128;
    const int h  = blockIdx.y;
    const int b  = blockIdx.z;
    const int kt0 = split * 16;

    // Q B-frags: B[k=d][n=q], lane: q=l32 (own row), d = t*16 + hi*8 + j
    short8 qB[4];
    {
        const long qbase = (long)(b * 2048 + q0 + wave * 32 + l32) * 1024 + h * 64 + hi * 8;
#pragma unroll
        for (int t = 0; t < 4; t++) qB[t] = *(const short8*)&Q[qbase + t * 16];
    }

    const int sr = tid >> 3;
    const int scol = (((tid & 7) ^ (sr & 7)) << 3);
    const short* Kp = Kb + (long)(b * 2048) * 1024 + h * 64;
    const short* Vp = Vt + ((long)b << 21) + (long)h * 64 * 2048;

    f32x16 o[2] = {};
    float lsum = 0.0f;
    short* const psw = &Ps[wave][0];

    // prologue: stage K tile kt0 into Ks[0]
#pragma unroll
    for (int i = 0; i < 2; i++) {
        int r = i * 32 + sr;
        gload16(&Kp[(long)(kt0 * 64 + r) * 1024 + scol], &Ks[0][i * 2048 + wave * 512]);
    }
    __syncthreads();

    for (int t = 0; t < 16; t++) {
        const int cur = t & 1;
        const int kb = (kt0 + t) * 64;

        // stage V(kt) — all waves done reading Vs at previous end barrier
#pragma unroll
        for (int i = 0; i < 2; i++) {
            int r = i * 32 + sr;
            gload16(&Vp[(long)r * 2048 + kb + scol], &Vs[i * 2048 + wave * 512]);
        }

        // S^T: two 32(kv) x 32(q) tiles, contraction d=64 in 4 steps
#pragma unroll
        for (int kvt = 0; kvt < 2; kvt++) {
            const int row = kvt * 32 + l32;
            f32x16 st = {};
#pragma unroll
            for (int step = 0; step < 4; step++) {
                short8 ak = *(short8*)&Ks[cur][row * 64 + (((step * 2 + hi) ^ sw) << 3)];
                st = __builtin_amdgcn_mfma_f32_32x32x16_bf16(ak, qB[step], st, 0, 0, 0);
            }
            // exp + pack: reg r -> kv = kvt*32 + (r&3) + 8*(r>>2) + 4*hi, q = l32
#pragma unroll
            for (int g = 0; g < 4; g++) {
                float p0 = __builtin_amdgcn_exp2f(st[g * 4 + 0]);
                float p1 = __builtin_amdgcn_exp2f(st[g * 4 + 1]);
                float p2 = __builtin_amdgcn_exp2f(st[g * 4 + 2]);
                float p3 = __builtin_amdgcn_exp2f(st[g * 4 + 3]);
                lsum += (p0 + p1) + (p2 + p3);
                u32 a0 = __float_as_uint(p0) + 0x8000u;
                u32 a1 = __float_as_uint(p1) + 0x8000u;
                u32 a2 = __float_as_uint(p2) + 0x8000u;
                u32 a3 = __float_as_uint(p3) + 0x8000u;
                u32x2 w;
                w[0] = __builtin_amdgcn_perm(a1, a0, 0x07060302u);
                w[1] = __builtin_amdgcn_perm(a3, a2, 0x07060302u);
                *(u32x2*)((char*)psw + l32 * 128 + (((kvt * 4 + g) ^ sw) << 4) + hi * 8) = w;
            }
        }

        // P B-frags (wave-private; no barrier)
        short8 pB[4];
#pragma unroll
        for (int step = 0; step < 4; step++)
            pB[step] = *(short8*)&psw[l32 * 64 + (((step * 2 + hi) ^ sw) << 3)];

        // mid barrier: V(kt) drained & visible; all K[cur] reads done
        __syncthreads();

        // prefetch K(kt+1) — drained at end barrier
        if (t < 15) {
            const int kbn = kb + 64;
#pragma unroll
            for (int i = 0; i < 2; i++) {
                int r = i * 32 + sr;
                gload16(&Kp[(long)(kbn + r) * 1024 + scol],
                        &Ks[cur ^ 1][i * 2048 + wave * 512]);
            }
        }

        // O^T = V^T . P^T : two 32(d) x 32(q) tiles
#pragma unroll
        for (int dt = 0; dt < 2; dt++) {
            const int row = dt * 32 + l32;
#pragma unroll
            for (int step = 0; step < 4; step++) {
                short8 av = *(short8*)&Vs[row * 64 + (((step * 2 + hi) ^ sw) << 3)];
                o[dt] = __builtin_amdgcn_mfma_f32_32x32x16_bf16(av, pB[step], o[dt], 0, 0, 0);
            }
        }

        // end barrier: K(kt+1) drained; Vs reads done
        __syncthreads();
    }

    // reduce lsum across the two hi halves (complementary kv rows), normalize
    lsum += __shfl_xor(lsum, 32, 64);
    const float inv = 1.0f / lsum;
    const int q = q0 + wave * 32 + l32;
    if (hi == 0) L[split * 65536 + (b * 16 + h) * 2048 + q] = lsum;
    const long rbase = (long)split * 4194304 + (long)(b * 2048 + q) * 1024 + h * 64;
#pragma unroll
    for (int dt = 0; dt < 2; dt++) {
#pragma unroll
        for (int g = 0; g < 4; g++) {
            short4v pk;
#pragma unroll
            for (int i = 0; i < 4; i++) pk[i] = f2bf(o[dt][g * 4 + i] * inv);
            *(short4v*)&Pp[rbase + dt * 32 + g * 8 + hi * 4] = pk;
        }
    }
}

// ---------------------------------------------------------------------------
// combine: AO = (l1*O1n + l2*O2n)/(l1+l2). 4096 blocks x 256 thr, 4 elems/thr.
// ---------------------------------------------------------------------------
__global__ __launch_bounds__(256) void combine(const short* __restrict__ Pp,
                                               const float* __restrict__ L,
                                               short* __restrict__ AO) {
    const int row = blockIdx.x;          // 0..4095
    const int b = row >> 11, q = row & 2047;
    const int col = threadIdx.x * 4;
    const int h = col >> 6;
    const float l1 = L[(b * 16 + h) * 2048 + q];
    const float l2 = L[65536 + (b * 16 + h) * 2048 + q];
    const float inv = 1.0f / (l1 + l2);
    const float w1 = l1 * inv, w2 = l2 * inv;
    const long idx = (long)row * 1024 + col;
    short4v p1 = *(const short4v*)&Pp[idx];
    short4v p2 = *(const short4v*)&Pp[4194304 + idx];
    short4v ov;
#pragma unroll
    for (int i = 0; i < 4; i++)
        ov[i] = f2bf(bf2f(p1[i]) * w1 + bf2f(p2[i]) * w2);
    *(short4v*)&AO[idx] = ov;
}

// ---------------------------------------------------------------------------
// Final GEMM: out = AO @ Wc^T + bc, fp32 out. 64x128 tiles, BK=64, swizzled.
// 512 blocks.
// ---------------------------------------------------------------------------
__global__ __launch_bounds__(256) void gemm_final(const short* __restrict__ A,
                                                  const short* __restrict__ W,
                                                  const float* __restrict__ bias,
                                                  float* __restrict__ C) {
    __shared__ short As[64 * 64];
    __shared__ short Bs[128 * 64];
    const int K = 1024;
    const int tid  = threadIdx.x;
    const int lane = tid & 63;
    const int wave = tid >> 6;
    const int quad = lane >> 4;
    const int l16  = lane & 15;
    const int bid = blockIdx.x;
    const int m0 = (bid >> 3) * 64;
    const int n0 = (bid & 7) * 128;
    const int wm = (wave >> 1) * 32;
    const int wn = (wave & 1) * 64;

    f32x4 acc[2][4] = {};
    const int sr = tid >> 3;
    const int scol = (((tid & 7) ^ (sr & 7)) << 3);
    const int fo_a = ((quad ^ (l16 & 7)) << 3);
    const int fo_b = (((4 + quad) ^ (l16 & 7)) << 3);

    for (int k0 = 0; k0 < K; k0 += 64) {
#pragma unroll
        for (int i = 0; i < 2; i++) {
            int r = i * 32 + sr;
            gload16(&A[(long)(m0 + r) * K + k0 + scol], &As[i * 2048 + wave * 512]);
        }
#pragma unroll
        for (int i = 0; i < 4; i++) {
            int r = i * 32 + sr;
            gload16(&W[(long)(n0 + r) * K + k0 + scol], &Bs[i * 2048 + wave * 512]);
        }
        __syncthreads();
        short8 bfr[4][2];
#pragma unroll
        for (int ni = 0; ni < 4; ni++) {
            const int row = wn + ni * 16 + l16;
            bfr[ni][0] = *(short8*)&Bs[row * 64 + fo_a];
            bfr[ni][1] = *(short8*)&Bs[row * 64 + fo_b];
        }
#pragma unroll
        for (int mi = 0; mi < 2; mi++) {
            const int row = wm + mi * 16 + l16;
            short8 af0 = *(short8*)&As[row * 64 + fo_a];
            short8 af1 = *(short8*)&As[row * 64 + fo_b];
#pragma unroll
            for (int ni = 0; ni < 4; ni++) {
                acc[mi][ni] = __builtin_amdgcn_mfma_f32_16x16x32_bf16(af0, bfr[ni][0],
                                                                      acc[mi][ni], 0, 0, 0);
                acc[mi][ni] = __builtin_amdgcn_mfma_f32_16x16x32_bf16(af1, bfr[ni][1],
                                                                      acc[mi][ni], 0, 0, 0);
            }
        }
        __syncthreads();
    }

#pragma unroll
    for (int mi = 0; mi < 2; mi++) {
#pragma unroll
        for (int ni = 0; ni < 4; ni++) {
            const int n = n0 + wn + ni * 16 + l16;
            const float bv = bias[n];
            const int mbase = m0 + wm + mi * 16 + quad * 4;
#pragma unroll
            for (int r = 0; r < 4; r++)
                C[(long)(mbase + r) * 1024 + n] = acc[mi][ni][r] + bv;
        }
    }
}

// ---------------------------------------------------------------------------
extern "C" void kernel_launch(void* const* d_in, const int* in_sizes, int n_in,
                              void* d_out, int out_size, void* d_ws, size_t ws_size,
                              hipStream_t stream) {
    const float* X  = (const float*)d_in[0];
    const float* Wq = (const float*)d_in[1];
    const float* bq = (const float*)d_in[2];
    const float* Wk = (const float*)d_in[3];
    const float* bk = (const float*)d_in[4];
    const float* Wv = (const float*)d_in[5];
    const float* bv = (const float*)d_in[6];
    const float* Ws = (const float*)d_in[7];
    const float* bs = (const float*)d_in[8];
    const float* Wo = (const float*)d_in[9];
    const float* bo = (const float*)d_in[10];

    char* ws = (char*)d_ws;
    const long MB = 1 << 20;
    short* Xb   = (short*)(ws + 0 * MB);   // 8 MB; reused as AO after qkvwc
    short* Wcat = (short*)(ws + 8 * MB);   // 6 MB (Wq,Wk,Wv bf16)
    short* WmT  = (short*)(ws + 14 * MB);  // 2 MB
    short* Wob  = (short*)(ws + 16 * MB);  // 2 MB
    short* Wc   = (short*)(ws + 18 * MB);  // 2 MB
    float* bc   = (float*)(ws + 20 * MB);  // 4 KB
    short* Qb   = (short*)(ws + 21 * MB);  // 8 MB
    short* Kbf  = (short*)(ws + 29 * MB);  // 8 MB
    short* Vtb  = (short*)(ws + 37 * MB);  // 8 MB
    short* Pp   = (short*)(ws + 45 * MB);  // 16 MB (2 splits x 8 MB)
    float* L    = (float*)(ws + 61 * MB);  // 512 KB
    short* AO   = Xb;

    dim3 bb(256);

    prep<<<dim3(8704), bb, 0, stream>>>(X, Wq, Wk, Wv, Wo, Ws, bs, bo,
                                        Xb, Wcat, Wob, WmT, bc);
    gemm_qkvwc<<<dim3(1664), bb, 0, stream>>>(Xb, Wcat, Wob, WmT, bq, bk, bv,
                                              Qb, Kbf, Vtb, Wc);
    attn_kernel<<<dim3(32, 16, 2), bb, 0, stream>>>(Qb, Kbf, Vtb, Pp, L);
    combine<<<dim3(4096), bb, 0, stream>>>(Pp, L, AO);
    gemm_final<<<dim3(512), bb, 0, stream>>>(AO, Wc, bc, (float*)d_out);
}